// Round 8
// 2845.292 us; speedup vs baseline: 1.2437x; 1.2437x over previous
//
#include <hip/hip_runtime.h>
#include <stdint.h>

#define NE 195480
#define NM 10242
#define NG 65160
#define DD 512
#define NOUT 471

typedef __attribute__((ext_vector_type(8))) short bf16x8;
typedef __attribute__((ext_vector_type(4))) float f32x4;
typedef __attribute__((ext_vector_type(8))) unsigned short ushort8;

__device__ __forceinline__ float bf2f(unsigned short u) {
    union { unsigned int i; float f; } v; v.i = ((unsigned int)u) << 16; return v.f;
}
__device__ __forceinline__ unsigned short f2bf(float f) {
    union { float f; unsigned int u; } v; v.f = f;
    unsigned int x = v.u;
    return (unsigned short)((x + 0x7fffu + ((x >> 16) & 1u)) >> 16);
}
__device__ __forceinline__ float silu_f(float x) { return x / (1.f + __expf(-x)); }

__device__ __forceinline__ ushort8 cvt8(const float* __restrict__ p) {
    const f32x4 lo = *(const f32x4*)p;
    const f32x4 hi = *(const f32x4*)(p + 4);
    ushort8 r;
    #pragma unroll
    for (int j = 0; j < 4; ++j) { r[j] = f2bf(lo[j]); r[j + 4] = f2bf(hi[j]); }
    return r;
}

enum { A_PLAIN = 0, A_EDGE = 1, A_NODE = 2 };
enum { E_BIAS_BF16 = 0, E_SILU_BF16 = 1, E_SCATTER = 2, E_RESID_BF16 = 3, E_OUT_F32 = 4 };

// C = epilogue(A @ B + bias), 128x128 tile, BK=64, 256 threads = 4 waves in
// 2x2 grid; each wave owns a 64x64 quadrant (acc[4][4] of 16x16 frags).
// B comes from pre-transposed bf16 weights wT[n][k] (row-contiguous in k) so
// both A and B fragments are ds_read_b128. LDS layout: [row][64 k] bf16 with
// XOR swizzle chunk^=(row&7) (16B chunks) -> 2-way bank aliasing (free).
// Per K-step per wave: 32 MFMA (16x16x32 bf16), 16 ds_read_b128, 8 staged
// 16B chunks. A sources: bf16 workspace, or f32 gathers (converted at stage).
template<int AMODE, int EPI>
__global__ __launch_bounds__(256)
void gemm128(const unsigned short* __restrict__ A,
             const unsigned short* __restrict__ Bw,   // bf16 [Npad=512][K]
             const float* __restrict__ bias,
             int M, int N, int K,
             const float* __restrict__ mesh,
             const float* __restrict__ gridf,
             const unsigned short* __restrict__ e0,
             const int* __restrict__ esrc,
             const int* __restrict__ edst,
             const float* __restrict__ aggIn,
             float* __restrict__ aggOut,
             unsigned short* __restrict__ outB,
             float* __restrict__ outF)
{
    __shared__ unsigned short As[128 * 64];
    __shared__ unsigned short Bs[128 * 64];

    const int tid  = threadIdx.x;
    const int bm   = blockIdx.x, bn = blockIdx.y;
    const int w    = tid >> 6;
    const int lane = tid & 63;
    const int quad = lane >> 4;
    const int ln   = lane & 15;
    const int wr   = w >> 1;      // wave row (0..1) -> rows [wr*64, wr*64+64)
    const int wc   = w & 1;       // wave col (0..1) -> cols [wc*64, wc*64+64)

    // staging roles: thread covers 4 chunks (one per 32-row group)
    const int srow = tid >> 3;    // 0..31 : row within group
    const int sc   = tid & 7;     // 0..7  : 8-elem chunk within 64-k row

    // gather indices are per-row constants -> hoist out of the K loop
    int gsrc[4], gdst[4];
    if (AMODE == A_EDGE) {
        #pragma unroll
        for (int i = 0; i < 4; ++i) {
            const int arow = bm * 128 + i * 32 + srow;
            gsrc[i] = (arow < M) ? esrc[arow] : 0;
            gdst[i] = (arow < M) ? edst[arow] : 0;
        }
    }

    f32x4 acc[4][4] = {};

    for (int k0 = 0; k0 < K; k0 += 64) {
        // ---- global -> registers ----
        ushort8 av[4], bv[4];
        #pragma unroll
        for (int i = 0; i < 4; ++i) {
            const int row  = i * 32 + srow;
            const int arow = bm * 128 + row;
            const int kk   = k0 + sc * 8;
            ushort8 t = {0, 0, 0, 0, 0, 0, 0, 0};
            if (AMODE == A_PLAIN) {
                if (arow < M) t = *(const ushort8*)(A + (size_t)arow * K + kk);
            } else if (AMODE == A_EDGE) {
                if (k0 < 512) {
                    if (arow < M) t = cvt8(mesh + (size_t)gsrc[i] * 512 + kk);
                } else if (k0 < 1024) {
                    if (arow < M) t = cvt8(gridf + (size_t)gdst[i] * 512 + (kk - 512));
                } else {
                    if (arow < M) t = *(const ushort8*)(e0 + (size_t)arow * 512 + (kk - 1024));
                }
            } else { // A_NODE: [grid f32 | agg f32]
                if (k0 < 512) {
                    if (arow < M) t = cvt8(gridf + (size_t)arow * 512 + kk);
                } else {
                    if (arow < M) t = cvt8(aggIn + (size_t)arow * 512 + (kk - 512));
                }
            }
            av[i] = t;
            // B: always in-bounds (wT zero-padded to Npad=512 rows)
            bv[i] = *(const ushort8*)(Bw + (size_t)(bn * 128 + row) * K + kk);
        }
        __syncthreads();   // previous compute done reading LDS
        #pragma unroll
        for (int i = 0; i < 4; ++i) {
            const int row = i * 32 + srow;
            const int swz = (sc ^ (row & 7)) * 8;
            *(ushort8*)(As + row * 64 + swz) = av[i];
            *(ushort8*)(Bs + row * 64 + swz) = bv[i];
        }
        __syncthreads();   // staging visible

        // ---- compute: 2 k-halves x 16 MFMA ----
        #pragma unroll
        for (int kt = 0; kt < 2; ++kt) {
            bf16x8 af[4], bfv[4];
            #pragma unroll
            for (int m = 0; m < 4; ++m) {
                const int r = wr * 64 + m * 16 + ln;
                af[m] = *(const bf16x8*)(As + r * 64 + (((kt * 4 + quad) ^ (r & 7)) * 8));
            }
            #pragma unroll
            for (int n = 0; n < 4; ++n) {
                const int r = wc * 64 + n * 16 + ln;
                bfv[n] = *(const bf16x8*)(Bs + r * 64 + (((kt * 4 + quad) ^ (r & 7)) * 8));
            }
            #pragma unroll
            for (int m = 0; m < 4; ++m)
                #pragma unroll
                for (int n = 0; n < 4; ++n)
                    acc[m][n] = __builtin_amdgcn_mfma_f32_16x16x32_bf16(af[m], bfv[n], acc[m][n], 0, 0, 0);
        }
    }

    // ---- epilogue ----
    #pragma unroll
    for (int n = 0; n < 4; ++n) {
        const int col_g = bn * 128 + wc * 64 + n * 16 + ln;
        const bool col_ok = (col_g < N);
        const float bcol = col_ok ? bias[col_g] : 0.f;
        #pragma unroll
        for (int m = 0; m < 4; ++m) {
            #pragma unroll
            for (int r = 0; r < 4; ++r) {
                const int row_g = bm * 128 + wr * 64 + m * 16 + quad * 4 + r;
                if (row_g >= M || !col_ok) continue;
                float v = acc[m][n][r] + bcol;
                if (EPI == E_BIAS_BF16) {
                    outB[(size_t)row_g * N + col_g] = f2bf(v);
                } else if (EPI == E_SILU_BF16) {
                    outB[(size_t)row_g * N + col_g] = f2bf(silu_f(v));
                } else if (EPI == E_SCATTER) {
                    v += bf2f(e0[(size_t)row_g * 512 + col_g]);   // residual e = e0 + mlp(..)
                    atomicAdd(&aggOut[(size_t)edst[row_g] * 512 + col_g], v);
                } else if (EPI == E_RESID_BF16) {
                    v += gridf[(size_t)row_g * 512 + col_g];
                    outB[(size_t)row_g * N + col_g] = f2bf(v);
                } else { // E_OUT_F32
                    outF[(size_t)row_g * N + col_g] = v;
                }
            }
        }
    }
}

// Transpose-convert weights: w f32 [K][N] -> wT bf16 [Npad][K],
// zero-padded rows N..Npad. Coalesced via 64x64 LDS tile.
__global__ __launch_bounds__(256)
void wconv(const float* __restrict__ w, unsigned short* __restrict__ wT,
           int K, int N, int Npad)
{
    __shared__ float t[64][65];
    const int tid = threadIdx.x;
    const int bk = blockIdx.x * 64, bn = blockIdx.y * 64;
    const int cc = tid & 63, rr = tid >> 6;
    #pragma unroll
    for (int i = 0; i < 16; ++i) {
        const int k = rr + i * 4;
        float v = 0.f;
        if (bk + k < K && bn + cc < N) v = w[(size_t)(bk + k) * N + bn + cc];
        t[k][cc] = v;
    }
    __syncthreads();
    #pragma unroll
    for (int i = 0; i < 16; ++i) {
        const int n = rr + i * 4;
        if (bn + n < Npad && bk + cc < K)
            wT[(size_t)(bn + n) * K + bk + cc] = f2bf(t[cc][n]);
    }
}

// h = silu(attrs @ emb_w0 + emb_b0), K=4 — one thread per output element.
__global__ __launch_bounds__(256)
void embed_l1(const float* __restrict__ attrs,
              const float* __restrict__ w0,
              const float* __restrict__ b0,
              unsigned short* __restrict__ h)
{
    const long long idx = (long long)blockIdx.x * 256 + threadIdx.x;
    if (idx >= (long long)NE * 512) return;
    const int row = (int)(idx >> 9);
    const int c = (int)(idx & 511);
    float acc = b0[c];
    #pragma unroll
    for (int k = 0; k < 4; ++k)
        acc += attrs[row * 4 + k] * w0[k * 512 + c];
    h[idx] = f2bf(silu_f(acc));
}

extern "C" void kernel_launch(void* const* d_in, const int* in_sizes, int n_in,
                              void* d_out, int out_size, void* d_ws, size_t ws_size,
                              hipStream_t stream)
{
    const float* mesh    = (const float*)d_in[0];
    const float* gridf   = (const float*)d_in[1];
    const float* attrs   = (const float*)d_in[2];
    const int*   esrc    = (const int*)d_in[3];
    const int*   edst    = (const int*)d_in[4];
    const float* emb_w0  = (const float*)d_in[5];
    const float* emb_b0  = (const float*)d_in[6];
    const float* emb_w1  = (const float*)d_in[7];
    const float* emb_b1  = (const float*)d_in[8];
    const float* edge_w0 = (const float*)d_in[9];
    const float* edge_b0 = (const float*)d_in[10];
    const float* edge_w1 = (const float*)d_in[11];
    const float* edge_b1 = (const float*)d_in[12];
    const float* node_w0 = (const float*)d_in[13];
    const float* node_b0 = (const float*)d_in[14];
    const float* node_w1 = (const float*)d_in[15];
    const float* node_b1 = (const float*)d_in[16];
    const float* out_w0  = (const float*)d_in[17];
    const float* out_b0  = (const float*)d_in[18];
    const float* out_w1  = (const float*)d_in[19];
    const float* out_b1  = (const float*)d_in[20];

    // ws layout (UNCHANGED footprint vs baseline, 533,790,720 B total):
    //   e0 (NE*512 bf16) | hb (NE*512 bf16) | agg (NG*512 f32)
    // Weight transposes live in scratch that is dead when they're needed:
    //   - d_out (122 MB, untouched until G8) holds the six weights for G2..G7;
    //     G8 fully overwrites d_out afterwards.
    //   - out_w1T (live DURING G8) is converted into the agg region after G5
    //     (agg dead once G5 consumed it). Re-done each graph replay.
    char* ws = (char*)d_ws;
    unsigned short* e0  = (unsigned short*)ws;
    unsigned short* hb  = (unsigned short*)(ws + (size_t)NE * 512 * 2);
    float*          agg = (float*)(ws + (size_t)2 * NE * 512 * 2);
    unsigned short* g2 = e0;   // reuse e0 region for grid2 (e0 dead after G4)

    unsigned short* wTp = (unsigned short*)d_out;     // scratch until G8
    unsigned short* emb_w1T  = wTp;
    unsigned short* edge_w0T = emb_w1T  + 512 * 512;
    unsigned short* edge_w1T = edge_w0T + 512 * 1536;
    unsigned short* node_w0T = edge_w1T + 512 * 512;
    unsigned short* node_w1T = node_w0T + 512 * 1024;
    unsigned short* out_w0T  = node_w1T + 512 * 512;
    unsigned short* out_w1T  = (unsigned short*)agg;  // converted after G5

    hipMemsetAsync(agg, 0, (size_t)NG * 512 * sizeof(float), stream);

    dim3 blk(256);
    // weight transpose-convert for G2..G7 (bf16 [n][k]) into d_out scratch
    { dim3 g( 8, 8); wconv<<<g, blk, 0, stream>>>(emb_w1,  emb_w1T,   512, 512, 512); }
    { dim3 g(24, 8); wconv<<<g, blk, 0, stream>>>(edge_w0, edge_w0T, 1536, 512, 512); }
    { dim3 g( 8, 8); wconv<<<g, blk, 0, stream>>>(edge_w1, edge_w1T,  512, 512, 512); }
    { dim3 g(16, 8); wconv<<<g, blk, 0, stream>>>(node_w0, node_w0T, 1024, 512, 512); }
    { dim3 g( 8, 8); wconv<<<g, blk, 0, stream>>>(node_w1, node_w1T,  512, 512, 512); }
    { dim3 g( 8, 8); wconv<<<g, blk, 0, stream>>>(out_w0,  out_w0T,   512, 512, 512); }

    // L1: hb = silu(attrs @ emb_w0 + b)
    embed_l1<<<(int)(((long long)NE * 512 + 255) / 256), blk, 0, stream>>>(attrs, emb_w0, emb_b0, hb);

    const int gmE = (NE + 127) / 128;   // 1528
    const int gmG = (NG + 127) / 128;   // 510

    // G2: e0 = hb @ emb_w1 + b
    { dim3 g(gmE, 4); gemm128<A_PLAIN, E_BIAS_BF16><<<g, blk, 0, stream>>>(hb, emb_w1T, emb_b1, NE, 512, 512,
        nullptr, nullptr, nullptr, nullptr, nullptr, nullptr, nullptr, e0, nullptr); }
    // G3: hb = silu([mesh[src] | grid[dst] | e0] @ edge_w0 + b)
    { dim3 g(gmE, 4); gemm128<A_EDGE, E_SILU_BF16><<<g, blk, 0, stream>>>(nullptr, edge_w0T, edge_b0, NE, 512, 1536,
        mesh, gridf, e0, esrc, edst, nullptr, nullptr, hb, nullptr); }
    // G4: agg[dst[r]] += e0[r] + hb @ edge_w1 + b   (fused segment_sum)
    { dim3 g(gmE, 4); gemm128<A_PLAIN, E_SCATTER><<<g, blk, 0, stream>>>(hb, edge_w1T, edge_b1, NE, 512, 512,
        nullptr, nullptr, e0, nullptr, edst, nullptr, agg, nullptr, nullptr); }
    // G5: hb = silu([grid | agg] @ node_w0 + b)
    { dim3 g(gmG, 4); gemm128<A_NODE, E_SILU_BF16><<<g, blk, 0, stream>>>(nullptr, node_w0T, node_b0, NG, 512, 1024,
        nullptr, gridf, nullptr, nullptr, nullptr, agg, nullptr, hb, nullptr); }
    // agg now dead -> convert out_w1 into it for G8
    { dim3 g( 8, 8); wconv<<<g, blk, 0, stream>>>(out_w1, out_w1T, 512, 471, 512); }
    // G6: g2 = grid + hb @ node_w1 + b
    { dim3 g(gmG, 4); gemm128<A_PLAIN, E_RESID_BF16><<<g, blk, 0, stream>>>(hb, node_w1T, node_b1, NG, 512, 512,
        nullptr, gridf, nullptr, nullptr, nullptr, nullptr, nullptr, g2, nullptr); }
    // G7: hb = silu(g2 @ out_w0 + b)
    { dim3 g(gmG, 4); gemm128<A_PLAIN, E_SILU_BF16><<<g, blk, 0, stream>>>(g2, out_w0T, out_b0, NG, 512, 512,
        nullptr, nullptr, nullptr, nullptr, nullptr, nullptr, nullptr, hb, nullptr); }
    // G8: out = hb @ out_w1 + b  (fp32 store, N=471; overwrites all d_out)
    { dim3 g(gmG, 4); gemm128<A_PLAIN, E_OUT_F32><<<g, blk, 0, stream>>>(hb, out_w1T, out_b1, NG, NOUT, 512,
        nullptr, nullptr, nullptr, nullptr, nullptr, nullptr, nullptr, nullptr, (float*)d_out); }
}

// Round 9
// 2525.096 us; speedup vs baseline: 1.4014x; 1.1268x over previous
//
#include <hip/hip_runtime.h>
#include <stdint.h>

#define NE 195480
#define NM 10242
#define NG 65160
#define DD 512
#define NOUT 471

typedef __attribute__((ext_vector_type(8))) short bf16x8;
typedef __attribute__((ext_vector_type(4))) float f32x4;
typedef __attribute__((ext_vector_type(8))) unsigned short ushort8;

__device__ __forceinline__ float bf2f(unsigned short u) {
    union { unsigned int i; float f; } v; v.i = ((unsigned int)u) << 16; return v.f;
}
__device__ __forceinline__ unsigned short f2bf(float f) {
    union { float f; unsigned int u; } v; v.f = f;
    unsigned int x = v.u;
    return (unsigned short)((x + 0x7fffu + ((x >> 16) & 1u)) >> 16);
}
__device__ __forceinline__ float silu_f(float x) { return x / (1.f + __expf(-x)); }

__device__ __forceinline__ ushort8 cvt8(const float* __restrict__ p) {
    const f32x4 lo = *(const f32x4*)p;
    const f32x4 hi = *(const f32x4*)(p + 4);
    ushort8 r;
    #pragma unroll
    for (int j = 0; j < 4; ++j) { r[j] = f2bf(lo[j]); r[j + 4] = f2bf(hi[j]); }
    return r;
}

// async global->LDS, 16B per lane. LDS dest must be lane-linear (wave base +
// lane*16); global source is per-lane (gathers OK).
__device__ __forceinline__ void gl_lds16(const unsigned short* g, unsigned short* l) {
    __builtin_amdgcn_global_load_lds(
        (const __attribute__((address_space(1))) unsigned int*)g,
        (__attribute__((address_space(3))) unsigned int*)l, 16, 0, 0);
}

enum { A_PLAIN = 0, A_EDGE = 1, A_NODE = 2 };
enum { E_BIAS_BF16 = 0, E_SILU_BF16 = 1, E_SCATTER = 2, E_RESID_BF16 = 3, E_OUT_F32 = 4 };

// C = epilogue(A @ B + bias), 128x128 tile, BK=64, 4 waves (2x2), m97-style
// staging: global_load_lds dwordx4 direct to LDS, no VGPR round trip. All A/B
// sources are bf16 (f32 inputs pre-converted once). Swizzle is applied on the
// GLOBAL source chunk (sc^(srow&7)) with linear LDS writes; ds_read applies
// the same XOR -> bank-conflict-free (verified 0 conflicts in R8).
// Grid: blockIdx.x = bn (fast) so the 4 N-tiles of one M-panel run together
// and share the A panel via L2/L3 (cuts A re-fetch 4x).
template<int AMODE, int EPI>
__global__ __launch_bounds__(256)
void gemm128(const unsigned short* __restrict__ Asrc,   // PLAIN: A | EDGE: meshB | NODE: gridB
             const unsigned short* __restrict__ Asrc2,  // EDGE: gridB | NODE: aggB
             const unsigned short* __restrict__ Asrc3,  // EDGE: e0
             const unsigned short* __restrict__ Bw,     // bf16 [512][K]
             const float* __restrict__ bias,
             int M, int N, int K,
             const float* __restrict__ gridres,         // E_RESID residual (f32)
             const unsigned short* __restrict__ e0res,  // E_SCATTER residual (bf16)
             const int* __restrict__ esrc,
             const int* __restrict__ edst,
             float* __restrict__ aggOut,
             unsigned short* __restrict__ outB,
             float* __restrict__ outF)
{
    __shared__ unsigned short As[128 * 64];
    __shared__ unsigned short Bs[128 * 64];

    const int tid  = threadIdx.x;
    const int bn   = blockIdx.x, bm = blockIdx.y;
    const int w    = tid >> 6;
    const int lane = tid & 63;
    const int quad = lane >> 4;
    const int ln   = lane & 15;
    const int wr   = w >> 1;
    const int wc   = w & 1;

    // staging roles: thread (srow, sc) covers LDS slot (i*32+srow, sc) for i=0..3
    const int srow = tid >> 3;    // 0..31
    const int sc   = tid & 7;     // 0..7
    const int ck   = (sc ^ (srow & 7)) * 8;   // swizzled source chunk (elements)

    // per-row constants hoisted out of the K loop (rows clamped: OOB rows
    // compute garbage, epilogue guards stores)
    int arowc[4], gsrc[4], gdst[4];
    #pragma unroll
    for (int i = 0; i < 4; ++i) {
        int r = bm * 128 + i * 32 + srow;
        arowc[i] = (r < M) ? r : (M - 1);
        if (AMODE == A_EDGE) { gsrc[i] = esrc[arowc[i]]; gdst[i] = edst[arowc[i]]; }
    }

    f32x4 acc[4][4] = {};

    for (int k0 = 0; k0 < K; k0 += 64) {
        __syncthreads();   // previous compute done reading LDS
        #pragma unroll
        for (int i = 0; i < 4; ++i) {
            const int row = i * 32 + srow;
            const unsigned short* ga;
            if (AMODE == A_PLAIN) {
                ga = Asrc + (size_t)arowc[i] * K + k0 + ck;
            } else if (AMODE == A_EDGE) {
                if (k0 < 512)       ga = Asrc  + (size_t)gsrc[i] * 512 + k0 + ck;
                else if (k0 < 1024) ga = Asrc2 + (size_t)gdst[i] * 512 + (k0 - 512) + ck;
                else                ga = Asrc3 + (size_t)arowc[i] * 512 + (k0 - 1024) + ck;
            } else { // A_NODE
                if (k0 < 512)       ga = Asrc  + (size_t)arowc[i] * 512 + k0 + ck;
                else                ga = Asrc2 + (size_t)arowc[i] * 512 + (k0 - 512) + ck;
            }
            gl_lds16(ga, As + i * 2048 + tid * 8);
            gl_lds16(Bw + (size_t)(bn * 128 + row) * K + k0 + ck, Bs + i * 2048 + tid * 8);
        }
        __syncthreads();   // compiler drains vmcnt(0) before barrier -> staged

        #pragma unroll
        for (int kt = 0; kt < 2; ++kt) {
            bf16x8 af[4], bfv[4];
            #pragma unroll
            for (int m = 0; m < 4; ++m) {
                const int r = wr * 64 + m * 16 + ln;
                af[m] = *(const bf16x8*)(As + r * 64 + (((kt * 4 + quad) ^ (r & 7)) * 8));
            }
            #pragma unroll
            for (int n = 0; n < 4; ++n) {
                const int r = wc * 64 + n * 16 + ln;
                bfv[n] = *(const bf16x8*)(Bs + r * 64 + (((kt * 4 + quad) ^ (r & 7)) * 8));
            }
            #pragma unroll
            for (int m = 0; m < 4; ++m)
                #pragma unroll
                for (int n = 0; n < 4; ++n)
                    acc[m][n] = __builtin_amdgcn_mfma_f32_16x16x32_bf16(af[m], bfv[n], acc[m][n], 0, 0, 0);
        }
    }

    // ---- epilogue ----
    #pragma unroll
    for (int n = 0; n < 4; ++n) {
        const int col_g = bn * 128 + wc * 64 + n * 16 + ln;
        const bool col_ok = (col_g < N);
        const float bcol = col_ok ? bias[col_g] : 0.f;
        #pragma unroll
        for (int m = 0; m < 4; ++m) {
            #pragma unroll
            for (int r = 0; r < 4; ++r) {
                const int row_g = bm * 128 + wr * 64 + m * 16 + quad * 4 + r;
                if (row_g >= M || !col_ok) continue;
                float v = acc[m][n][r] + bcol;
                if (EPI == E_BIAS_BF16) {
                    outB[(size_t)row_g * N + col_g] = f2bf(v);
                } else if (EPI == E_SILU_BF16) {
                    outB[(size_t)row_g * N + col_g] = f2bf(silu_f(v));
                } else if (EPI == E_SCATTER) {
                    v += bf2f(e0res[(size_t)row_g * 512 + col_g]);  // e = e0 + mlp(..)
                    atomicAdd(&aggOut[(size_t)edst[row_g] * 512 + col_g], v);
                } else if (EPI == E_RESID_BF16) {
                    v += gridres[(size_t)row_g * 512 + col_g];
                    outB[(size_t)row_g * N + col_g] = f2bf(v);
                } else { // E_OUT_F32
                    outF[(size_t)row_g * N + col_g] = v;
                }
            }
        }
    }
}

// Transpose-convert weights: w f32 [K][N] -> wT bf16 [Npad][K], zero-padded.
__global__ __launch_bounds__(256)
void wconv(const float* __restrict__ w, unsigned short* __restrict__ wT,
           int K, int N, int Npad)
{
    __shared__ float t[64][65];
    const int tid = threadIdx.x;
    const int bk = blockIdx.x * 64, bn = blockIdx.y * 64;
    const int cc = tid & 63, rr = tid >> 6;
    #pragma unroll
    for (int i = 0; i < 16; ++i) {
        const int k = rr + i * 4;
        float v = 0.f;
        if (bk + k < K && bn + cc < N) v = w[(size_t)(bk + k) * N + bn + cc];
        t[k][cc] = v;
    }
    __syncthreads();
    #pragma unroll
    for (int i = 0; i < 16; ++i) {
        const int n = rr + i * 4;
        if (bn + n < Npad && bk + cc < K)
            wT[(size_t)(bn + n) * K + bk + cc] = f2bf(t[cc][n]);
    }
}

// flat f32 -> bf16 convert, 8 elems/thread
__global__ __launch_bounds__(256)
void cvtb(const float* __restrict__ in, unsigned short* __restrict__ out, long long n8)
{
    const long long i = (long long)blockIdx.x * 256 + threadIdx.x;
    if (i >= n8) return;
    *(ushort8*)(out + i * 8) = cvt8(in + i * 8);
}

// h = silu(attrs @ emb_w0 + emb_b0), K=4
__global__ __launch_bounds__(256)
void embed_l1(const float* __restrict__ attrs,
              const float* __restrict__ w0,
              const float* __restrict__ b0,
              unsigned short* __restrict__ h)
{
    const long long idx = (long long)blockIdx.x * 256 + threadIdx.x;
    if (idx >= (long long)NE * 512) return;
    const int row = (int)(idx >> 9);
    const int c = (int)(idx & 511);
    float acc = b0[c];
    #pragma unroll
    for (int k = 0; k < 4; ++k)
        acc += attrs[row * 4 + k] * w0[k * 512 + c];
    h[idx] = f2bf(silu_f(acc));
}

extern "C" void kernel_launch(void* const* d_in, const int* in_sizes, int n_in,
                              void* d_out, int out_size, void* d_ws, size_t ws_size,
                              hipStream_t stream)
{
    const float* mesh    = (const float*)d_in[0];
    const float* gridf   = (const float*)d_in[1];
    const float* attrs   = (const float*)d_in[2];
    const int*   esrc    = (const int*)d_in[3];
    const int*   edst    = (const int*)d_in[4];
    const float* emb_w0  = (const float*)d_in[5];
    const float* emb_b0  = (const float*)d_in[6];
    const float* emb_w1  = (const float*)d_in[7];
    const float* emb_b1  = (const float*)d_in[8];
    const float* edge_w0 = (const float*)d_in[9];
    const float* edge_b0 = (const float*)d_in[10];
    const float* edge_w1 = (const float*)d_in[11];
    const float* edge_b1 = (const float*)d_in[12];
    const float* node_w0 = (const float*)d_in[13];
    const float* node_b0 = (const float*)d_in[14];
    const float* node_w1 = (const float*)d_in[15];
    const float* node_b1 = (const float*)d_in[16];
    const float* out_w0  = (const float*)d_in[17];
    const float* out_b0  = (const float*)d_in[18];
    const float* out_w1  = (const float*)d_in[19];
    const float* out_b1  = (const float*)d_in[20];

    // ws (534 MB baseline footprint, unchanged): e0 | hb | agg
    //   e0 region (200 MB): e0 bf16 live G2..G4; then aggB bf16 at +133 MB
    //   (written after G4, read by G5); then g2 at base (written G6).
    // d_out (122.8 MB) scratch until G8: wT weights (4.7 MB) + meshB (10.5)
    //   + gridB (66.7) = 81.9 MB. G8 fully overwrites d_out.
    // out_w1T lives in agg f32 region (dead after agg->aggB cvt).
    char* ws = (char*)d_ws;
    unsigned short* e0  = (unsigned short*)ws;
    unsigned short* hb  = (unsigned short*)(ws + (size_t)NE * 512 * 2);
    float*          agg = (float*)(ws + (size_t)2 * NE * 512 * 2);
    unsigned short* g2   = e0;
    unsigned short* aggB = (unsigned short*)(ws + 133447680);  // in e0 region

    unsigned short* wTp = (unsigned short*)d_out;
    unsigned short* emb_w1T  = wTp;                       // 512*512
    unsigned short* edge_w0T = emb_w1T  + 512 * 512;      // 512*1536
    unsigned short* edge_w1T = edge_w0T + 512 * 1536;     // 512*512
    unsigned short* node_w0T = edge_w1T + 512 * 512;      // 512*1024
    unsigned short* node_w1T = node_w0T + 512 * 1024;     // 512*512
    unsigned short* out_w0T  = node_w1T + 512 * 512;      // 512*512
    unsigned short* meshB    = out_w0T  + 512 * 512;      // NM*512
    unsigned short* gridB    = meshB + (size_t)NM * 512;  // NG*512
    unsigned short* out_w1T  = (unsigned short*)agg;      // after agg dead

    hipMemsetAsync(agg, 0, (size_t)NG * 512 * sizeof(float), stream);

    dim3 blk(256);
    { dim3 g( 8, 8); wconv<<<g, blk, 0, stream>>>(emb_w1,  emb_w1T,   512, 512, 512); }
    { dim3 g(24, 8); wconv<<<g, blk, 0, stream>>>(edge_w0, edge_w0T, 1536, 512, 512); }
    { dim3 g( 8, 8); wconv<<<g, blk, 0, stream>>>(edge_w1, edge_w1T,  512, 512, 512); }
    { dim3 g(16, 8); wconv<<<g, blk, 0, stream>>>(node_w0, node_w0T, 1024, 512, 512); }
    { dim3 g( 8, 8); wconv<<<g, blk, 0, stream>>>(node_w1, node_w1T,  512, 512, 512); }
    { dim3 g( 8, 8); wconv<<<g, blk, 0, stream>>>(out_w0,  out_w0T,   512, 512, 512); }
    cvtb<<<(int)(((long long)NM * 512 / 8 + 255) / 256), blk, 0, stream>>>(mesh,  meshB, (long long)NM * 512 / 8);
    cvtb<<<(int)(((long long)NG * 512 / 8 + 255) / 256), blk, 0, stream>>>(gridf, gridB, (long long)NG * 512 / 8);

    // L1: hb = silu(attrs @ emb_w0 + b)
    embed_l1<<<(int)(((long long)NE * 512 + 255) / 256), blk, 0, stream>>>(attrs, emb_w0, emb_b0, hb);

    const int gmE = (NE + 127) / 128;   // 1528
    const int gmG = (NG + 127) / 128;   // 510

    // G2: e0 = hb @ emb_w1 + b
    { dim3 g(4, gmE); gemm128<A_PLAIN, E_BIAS_BF16><<<g, blk, 0, stream>>>(hb, nullptr, nullptr, emb_w1T, emb_b1,
        NE, 512, 512, nullptr, nullptr, nullptr, nullptr, nullptr, e0, nullptr); }
    // G3: hb = silu([meshB[src] | gridB[dst] | e0] @ edge_w0 + b)
    { dim3 g(4, gmE); gemm128<A_EDGE, E_SILU_BF16><<<g, blk, 0, stream>>>(meshB, gridB, e0, edge_w0T, edge_b0,
        NE, 512, 1536, nullptr, nullptr, esrc, edst, nullptr, hb, nullptr); }
    // G4: agg[dst[r]] += e0[r] + hb @ edge_w1 + b
    { dim3 g(4, gmE); gemm128<A_PLAIN, E_SCATTER><<<g, blk, 0, stream>>>(hb, nullptr, nullptr, edge_w1T, edge_b1,
        NE, 512, 512, nullptr, e0, nullptr, edst, agg, nullptr, nullptr); }
    // agg complete -> bf16 copy for G5's A (same rounding as before: A was
    // converted f32->bf16 at staging anyway)
    cvtb<<<(int)(((long long)NG * 512 / 8 + 255) / 256), blk, 0, stream>>>(agg, aggB, (long long)NG * 512 / 8);
    // G5: hb = silu([gridB | aggB] @ node_w0 + b)
    { dim3 g(4, gmG); gemm128<A_NODE, E_SILU_BF16><<<g, blk, 0, stream>>>(gridB, aggB, nullptr, node_w0T, node_b0,
        NG, 512, 1024, nullptr, nullptr, nullptr, nullptr, nullptr, hb, nullptr); }
    // agg f32 now dead -> convert out_w1 into its region for G8
    { dim3 g( 8, 8); wconv<<<g, blk, 0, stream>>>(out_w1, out_w1T, 512, 471, 512); }
    // G6: g2 = grid + hb @ node_w1 + b
    { dim3 g(4, gmG); gemm128<A_PLAIN, E_RESID_BF16><<<g, blk, 0, stream>>>(hb, nullptr, nullptr, node_w1T, node_b1,
        NG, 512, 512, gridf, nullptr, nullptr, nullptr, nullptr, g2, nullptr); }
    // G7: hb = silu(g2 @ out_w0 + b)
    { dim3 g(4, gmG); gemm128<A_PLAIN, E_SILU_BF16><<<g, blk, 0, stream>>>(g2, nullptr, nullptr, out_w0T, out_b0,
        NG, 512, 512, nullptr, nullptr, nullptr, nullptr, nullptr, hb, nullptr); }
    // G8: out = hb @ out_w1 + b (fp32, N=471; overwrites all d_out scratch)
    { dim3 g(4, gmG); gemm128<A_PLAIN, E_OUT_F32><<<g, blk, 0, stream>>>(hb, nullptr, nullptr, out_w1T, out_b1,
        NG, NOUT, 512, nullptr, nullptr, nullptr, nullptr, nullptr, nullptr, (float*)d_out); }
}

// Round 10
// 2244.788 us; speedup vs baseline: 1.5764x; 1.1249x over previous
//
#include <hip/hip_runtime.h>
#include <stdint.h>

#define NE 195480
#define NM 10242
#define NG 65160
#define DD 512
#define NOUT 471

typedef __attribute__((ext_vector_type(8))) short bf16x8;
typedef __attribute__((ext_vector_type(4))) float f32x4;
typedef __attribute__((ext_vector_type(8))) unsigned short ushort8;

__device__ __forceinline__ float bf2f(unsigned short u) {
    union { unsigned int i; float f; } v; v.i = ((unsigned int)u) << 16; return v.f;
}
__device__ __forceinline__ unsigned short f2bf(float f) {
    union { float f; unsigned int u; } v; v.f = f;
    unsigned int x = v.u;
    return (unsigned short)((x + 0x7fffu + ((x >> 16) & 1u)) >> 16);
}
__device__ __forceinline__ float silu_f(float x) { return x / (1.f + __expf(-x)); }

__device__ __forceinline__ ushort8 cvt8(const float* __restrict__ p) {
    const f32x4 lo = *(const f32x4*)p;
    const f32x4 hi = *(const f32x4*)(p + 4);
    ushort8 r;
    #pragma unroll
    for (int j = 0; j < 4; ++j) { r[j] = f2bf(lo[j]); r[j + 4] = f2bf(hi[j]); }
    return r;
}

// async global->LDS, 16B per lane. LDS dest lane-linear; global src per-lane.
__device__ __forceinline__ void gl_lds16(const unsigned short* g, unsigned short* l) {
    __builtin_amdgcn_global_load_lds(
        (const __attribute__((address_space(1))) unsigned int*)g,
        (__attribute__((address_space(3))) unsigned int*)l, 16, 0, 0);
}

enum { A_PLAIN = 0, A_EDGE = 1, A_NODE = 2 };
enum { E_BIAS_BF16 = 0, E_SILU_BF16 = 1, E_EADD_BF16 = 2, E_RESID_BF16 = 3, E_OUT_F32 = 4 };

// C = epilogue(A @ B + bias), 128x128 tile, BK=64, 4 waves (2x2), m97-style
// global_load_lds staging (R9: bank conflicts = 0, verified). Swizzle on the
// GLOBAL source chunk, linear LDS writes, same XOR on ds_read. blockIdx.x=bn
// (fast) so 4 N-tiles of one M-panel co-run and share the A panel in L2.
// E_EADD_BF16: e = e0 + mlp, written bf16 IN-PLACE over e0 (each element
// read->written once by its owner thread) — replaces the fp32 atomic scatter
// that was the R9 top cost (391 MB atomic RMW, serialization-bound).
template<int AMODE, int EPI>
__global__ __launch_bounds__(256)
void gemm128(const unsigned short* __restrict__ Asrc,   // PLAIN: A | EDGE: meshB | NODE: gridB
             const unsigned short* __restrict__ Asrc2,  // EDGE: gridB | NODE: aggB
             const unsigned short* __restrict__ Asrc3,  // EDGE: e0
             const unsigned short* __restrict__ Bw,     // bf16 [512][K]
             const float* __restrict__ bias,
             int M, int N, int K,
             const float* __restrict__ gridres,         // E_RESID residual (f32)
             const unsigned short* __restrict__ e0res,  // E_EADD residual (bf16)
             const int* __restrict__ esrc,
             const int* __restrict__ edst,
             unsigned short* __restrict__ outB,
             float* __restrict__ outF)
{
    __shared__ unsigned short As[128 * 64];
    __shared__ unsigned short Bs[128 * 64];

    const int tid  = threadIdx.x;
    const int bn   = blockIdx.x, bm = blockIdx.y;
    const int w    = tid >> 6;
    const int lane = tid & 63;
    const int quad = lane >> 4;
    const int ln   = lane & 15;
    const int wr   = w >> 1;
    const int wc   = w & 1;

    const int srow = tid >> 3;    // 0..31
    const int sc   = tid & 7;     // 0..7
    const int ck   = (sc ^ (srow & 7)) * 8;   // swizzled source chunk (elems)

    int arowc[4], gsrc[4], gdst[4];
    #pragma unroll
    for (int i = 0; i < 4; ++i) {
        int r = bm * 128 + i * 32 + srow;
        arowc[i] = (r < M) ? r : (M - 1);
        if (AMODE == A_EDGE) { gsrc[i] = esrc[arowc[i]]; gdst[i] = edst[arowc[i]]; }
    }

    f32x4 acc[4][4] = {};

    for (int k0 = 0; k0 < K; k0 += 64) {
        __syncthreads();   // previous compute done reading LDS
        #pragma unroll
        for (int i = 0; i < 4; ++i) {
            const int row = i * 32 + srow;
            const unsigned short* ga;
            if (AMODE == A_PLAIN) {
                ga = Asrc + (size_t)arowc[i] * K + k0 + ck;
            } else if (AMODE == A_EDGE) {
                if (k0 < 512)       ga = Asrc  + (size_t)gsrc[i] * 512 + k0 + ck;
                else if (k0 < 1024) ga = Asrc2 + (size_t)gdst[i] * 512 + (k0 - 512) + ck;
                else                ga = Asrc3 + (size_t)arowc[i] * 512 + (k0 - 1024) + ck;
            } else { // A_NODE
                if (k0 < 512)       ga = Asrc  + (size_t)arowc[i] * 512 + k0 + ck;
                else                ga = Asrc2 + (size_t)arowc[i] * 512 + (k0 - 512) + ck;
            }
            gl_lds16(ga, As + i * 2048 + tid * 8);
            gl_lds16(Bw + (size_t)(bn * 128 + row) * K + k0 + ck, Bs + i * 2048 + tid * 8);
        }
        __syncthreads();   // vmcnt(0) drained before barrier -> staged

        #pragma unroll
        for (int kt = 0; kt < 2; ++kt) {
            bf16x8 af[4], bfv[4];
            #pragma unroll
            for (int m = 0; m < 4; ++m) {
                const int r = wr * 64 + m * 16 + ln;
                af[m] = *(const bf16x8*)(As + r * 64 + (((kt * 4 + quad) ^ (r & 7)) * 8));
            }
            #pragma unroll
            for (int n = 0; n < 4; ++n) {
                const int r = wc * 64 + n * 16 + ln;
                bfv[n] = *(const bf16x8*)(Bs + r * 64 + (((kt * 4 + quad) ^ (r & 7)) * 8));
            }
            #pragma unroll
            for (int m = 0; m < 4; ++m)
                #pragma unroll
                for (int n = 0; n < 4; ++n)
                    acc[m][n] = __builtin_amdgcn_mfma_f32_16x16x32_bf16(af[m], bfv[n], acc[m][n], 0, 0, 0);
        }
    }

    // ---- epilogue ----
    #pragma unroll
    for (int n = 0; n < 4; ++n) {
        const int col_g = bn * 128 + wc * 64 + n * 16 + ln;
        const bool col_ok = (col_g < N);
        const float bcol = col_ok ? bias[col_g] : 0.f;
        #pragma unroll
        for (int m = 0; m < 4; ++m) {
            #pragma unroll
            for (int r = 0; r < 4; ++r) {
                const int row_g = bm * 128 + wr * 64 + m * 16 + quad * 4 + r;
                if (row_g >= M || !col_ok) continue;
                float v = acc[m][n][r] + bcol;
                if (EPI == E_BIAS_BF16) {
                    outB[(size_t)row_g * N + col_g] = f2bf(v);
                } else if (EPI == E_SILU_BF16) {
                    outB[(size_t)row_g * N + col_g] = f2bf(silu_f(v));
                } else if (EPI == E_EADD_BF16) {
                    v += bf2f(e0res[(size_t)row_g * 512 + col_g]);  // e = e0 + mlp
                    outB[(size_t)row_g * 512 + col_g] = f2bf(v);    // in-place over e0
                } else if (EPI == E_RESID_BF16) {
                    v += gridres[(size_t)row_g * 512 + col_g];
                    outB[(size_t)row_g * N + col_g] = f2bf(v);
                } else { // E_OUT_F32
                    outF[(size_t)row_g * N + col_g] = v;
                }
            }
        }
    }
}

// Transpose-convert weights: w f32 [K][N] -> wT bf16 [Npad][K], zero-padded.
__global__ __launch_bounds__(256)
void wconv(const float* __restrict__ w, unsigned short* __restrict__ wT,
           int K, int N, int Npad)
{
    __shared__ float t[64][65];
    const int tid = threadIdx.x;
    const int bk = blockIdx.x * 64, bn = blockIdx.y * 64;
    const int cc = tid & 63, rr = tid >> 6;
    #pragma unroll
    for (int i = 0; i < 16; ++i) {
        const int k = rr + i * 4;
        float v = 0.f;
        if (bk + k < K && bn + cc < N) v = w[(size_t)(bk + k) * N + bn + cc];
        t[k][cc] = v;
    }
    __syncthreads();
    #pragma unroll
    for (int i = 0; i < 16; ++i) {
        const int n = rr + i * 4;
        if (bn + n < Npad && bk + cc < K)
            wT[(size_t)(bn + n) * K + bk + cc] = f2bf(t[cc][n]);
    }
}

// flat f32 -> bf16 convert, 8 elems/thread
__global__ __launch_bounds__(256)
void cvtb(const float* __restrict__ in, unsigned short* __restrict__ out, long long n8)
{
    const long long i = (long long)blockIdx.x * 256 + threadIdx.x;
    if (i >= n8) return;
    *(ushort8*)(out + i * 8) = cvt8(in + i * 8);
}

// h = silu(attrs @ emb_w0 + emb_b0), K=4
__global__ __launch_bounds__(256)
void embed_l1(const float* __restrict__ attrs,
              const float* __restrict__ w0,
              const float* __restrict__ b0,
              unsigned short* __restrict__ h)
{
    const long long idx = (long long)blockIdx.x * 256 + threadIdx.x;
    if (idx >= (long long)NE * 512) return;
    const int row = (int)(idx >> 9);
    const int c = (int)(idx & 511);
    float acc = b0[c];
    #pragma unroll
    for (int k = 0; k < 4; ++k)
        acc += attrs[row * 4 + k] * w0[k * 512 + c];
    h[idx] = f2bf(silu_f(acc));
}

// Per-dst-node slot lists: fill[d] counter + slots[d][0..63] edge ids.
// 195K low-contention atomics (~65K counters, Poisson(3) degrees; P(deg>=64)~0).
__global__ __launch_bounds__(256)
void fillslots(const int* __restrict__ edst, unsigned* __restrict__ fill,
               unsigned* __restrict__ slots)
{
    const int i = blockIdx.x * 256 + threadIdx.x;
    if (i >= NE) return;
    const int d = edst[i];
    const unsigned p = atomicAdd(&fill[d], 1u);
    if (p < 64u) slots[(size_t)d * 64 + p] = (unsigned)i;
}

// aggB[g] = sum over edges with dst g of e[eid] (bf16 rows, f32 accum).
// Block g: 256 threads cover 512 cols (2 each); coalesced 512B row segments.
__global__ __launch_bounds__(256)
void segsum(const unsigned short* __restrict__ e,
            const unsigned* __restrict__ fill,
            const unsigned* __restrict__ slots,
            unsigned short* __restrict__ aggB)
{
    const int g = blockIdx.x;
    const int c = threadIdx.x;
    unsigned deg = fill[g]; if (deg > 64u) deg = 64u;
    float a0 = 0.f, a1 = 0.f;
    for (unsigned j = 0; j < deg; ++j) {
        const unsigned short* row = e + (size_t)slots[(size_t)g * 64 + j] * 512;
        a0 += bf2f(row[c]);
        a1 += bf2f(row[c + 256]);
    }
    aggB[(size_t)g * 512 + c]       = f2bf(a0);
    aggB[(size_t)g * 512 + c + 256] = f2bf(a1);
}

extern "C" void kernel_launch(void* const* d_in, const int* in_sizes, int n_in,
                              void* d_out, int out_size, void* d_ws, size_t ws_size,
                              hipStream_t stream)
{
    const float* mesh    = (const float*)d_in[0];
    const float* gridf   = (const float*)d_in[1];
    const float* attrs   = (const float*)d_in[2];
    const int*   esrc    = (const int*)d_in[3];
    const int*   edst    = (const int*)d_in[4];
    const float* emb_w0  = (const float*)d_in[5];
    const float* emb_b0  = (const float*)d_in[6];
    const float* emb_w1  = (const float*)d_in[7];
    const float* emb_b1  = (const float*)d_in[8];
    const float* edge_w0 = (const float*)d_in[9];
    const float* edge_b0 = (const float*)d_in[10];
    const float* edge_w1 = (const float*)d_in[11];
    const float* edge_b1 = (const float*)d_in[12];
    const float* node_w0 = (const float*)d_in[13];
    const float* node_b0 = (const float*)d_in[14];
    const float* node_w1 = (const float*)d_in[15];
    const float* node_b1 = (const float*)d_in[16];
    const float* out_w0  = (const float*)d_in[17];
    const float* out_b0  = (const float*)d_in[18];
    const float* out_w1  = (const float*)d_in[19];
    const float* out_b1  = (const float*)d_in[20];

    // ws (534 MB baseline footprint): e0/e/g2 (200 MB) | hb (200 MB) | r3 (133 MB)
    //   r3: aggB bf16 (66.7) | out_w1T (0.5) | fill (0.26) | slots (16.7) — no
    //   agg f32, no 133 MB memset, no agg cvtb.
    // d_out (122.8 MB) scratch until G8: 6 wT weights + meshB + gridB (81.9 MB).
    char* ws = (char*)d_ws;
    unsigned short* e0  = (unsigned short*)ws;            // e0 -> e (in-place) -> g2
    unsigned short* hb  = (unsigned short*)(ws + (size_t)NE * 512 * 2);
    char*           r3  = ws + (size_t)2 * NE * 512 * 2;  // 133,447,680 B region
    unsigned short* g2  = e0;

    unsigned short* aggB    = (unsigned short*)r3;              // 66,723,840 B
    unsigned short* out_w1T = (unsigned short*)(r3 + 66723840); //    524,288 B
    unsigned*       fillA   = (unsigned*)(r3 + 67248128);       //    260,640 B
    unsigned*       slots   = (unsigned*)(r3 + 67508768);       // 16,680,960 B (ends 84.2 MB)

    unsigned short* wTp = (unsigned short*)d_out;
    unsigned short* emb_w1T  = wTp;                       // 512*512
    unsigned short* edge_w0T = emb_w1T  + 512 * 512;      // 512*1536
    unsigned short* edge_w1T = edge_w0T + 512 * 1536;     // 512*512
    unsigned short* node_w0T = edge_w1T + 512 * 512;      // 512*1024
    unsigned short* node_w1T = node_w0T + 512 * 1024;     // 512*512
    unsigned short* out_w0T  = node_w1T + 512 * 512;      // 512*512
    unsigned short* meshB    = out_w0T  + 512 * 512;      // NM*512
    unsigned short* gridB    = meshB + (size_t)NM * 512;  // NG*512

    hipMemsetAsync(fillA, 0, (size_t)NG * sizeof(unsigned), stream);

    dim3 blk(256);
    { dim3 g( 8, 8); wconv<<<g, blk, 0, stream>>>(emb_w1,  emb_w1T,   512, 512, 512); }
    { dim3 g(24, 8); wconv<<<g, blk, 0, stream>>>(edge_w0, edge_w0T, 1536, 512, 512); }
    { dim3 g( 8, 8); wconv<<<g, blk, 0, stream>>>(edge_w1, edge_w1T,  512, 512, 512); }
    { dim3 g(16, 8); wconv<<<g, blk, 0, stream>>>(node_w0, node_w0T, 1024, 512, 512); }
    { dim3 g( 8, 8); wconv<<<g, blk, 0, stream>>>(node_w1, node_w1T,  512, 512, 512); }
    { dim3 g( 8, 8); wconv<<<g, blk, 0, stream>>>(out_w0,  out_w0T,   512, 512, 512); }
    { dim3 g( 8, 8); wconv<<<g, blk, 0, stream>>>(out_w1,  out_w1T,   512, 471, 512); }
    cvtb<<<(int)(((long long)NM * 512 / 8 + 255) / 256), blk, 0, stream>>>(mesh,  meshB, (long long)NM * 512 / 8);
    cvtb<<<(int)(((long long)NG * 512 / 8 + 255) / 256), blk, 0, stream>>>(gridf, gridB, (long long)NG * 512 / 8);
    fillslots<<<(NE + 255) / 256, blk, 0, stream>>>(edst, fillA, slots);

    // L1: hb = silu(attrs @ emb_w0 + b)
    embed_l1<<<(int)(((long long)NE * 512 + 255) / 256), blk, 0, stream>>>(attrs, emb_w0, emb_b0, hb);

    const int gmE = (NE + 127) / 128;   // 1528
    const int gmG = (NG + 127) / 128;   // 510

    // G2: e0 = hb @ emb_w1 + b
    { dim3 g(4, gmE); gemm128<A_PLAIN, E_BIAS_BF16><<<g, blk, 0, stream>>>(hb, nullptr, nullptr, emb_w1T, emb_b1,
        NE, 512, 512, nullptr, nullptr, nullptr, nullptr, e0, nullptr); }
    // G3: hb = silu([meshB[src] | gridB[dst] | e0] @ edge_w0 + b)
    { dim3 g(4, gmE); gemm128<A_EDGE, E_SILU_BF16><<<g, blk, 0, stream>>>(meshB, gridB, e0, edge_w0T, edge_b0,
        NE, 512, 1536, nullptr, nullptr, esrc, edst, hb, nullptr); }
    // G4: e = e0 + hb @ edge_w1 + b   (bf16, in-place over e0 — no atomics)
    { dim3 g(4, gmE); gemm128<A_PLAIN, E_EADD_BF16><<<g, blk, 0, stream>>>(hb, nullptr, nullptr, edge_w1T, edge_b1,
        NE, 512, 512, nullptr, e0, nullptr, nullptr, e0, nullptr); }
    // segment-sum by gather: aggB[g] = sum e[slots[g]]
    segsum<<<NG, blk, 0, stream>>>(e0, fillA, slots, aggB);
    // G5: hb = silu([gridB | aggB] @ node_w0 + b)
    { dim3 g(4, gmG); gemm128<A_NODE, E_SILU_BF16><<<g, blk, 0, stream>>>(gridB, aggB, nullptr, node_w0T, node_b0,
        NG, 512, 1024, nullptr, nullptr, nullptr, nullptr, hb, nullptr); }
    // G6: g2 = grid + hb @ node_w1 + b
    { dim3 g(4, gmG); gemm128<A_PLAIN, E_RESID_BF16><<<g, blk, 0, stream>>>(hb, nullptr, nullptr, node_w1T, node_b1,
        NG, 512, 512, gridf, nullptr, nullptr, nullptr, g2, nullptr); }
    // G7: hb = silu(g2 @ out_w0 + b)
    { dim3 g(4, gmG); gemm128<A_PLAIN, E_SILU_BF16><<<g, blk, 0, stream>>>(g2, nullptr, nullptr, out_w0T, out_b0,
        NG, 512, 512, nullptr, nullptr, nullptr, nullptr, hb, nullptr); }
    // G8: out = hb @ out_w1 + b (fp32, N=471; overwrites all d_out scratch)
    { dim3 g(4, gmG); gemm128<A_PLAIN, E_OUT_F32><<<g, blk, 0, stream>>>(hb, nullptr, nullptr, out_w1T, out_b1,
        NG, NOUT, 512, nullptr, nullptr, nullptr, nullptr, nullptr, (float*)d_out); }
}